// Round 2
// baseline (245.218 us; speedup 1.0000x reference)
//
#include <hip/hip_runtime.h>
#include <hip/hip_bf16.h>

// SparseLoRAMoE: out[t,d] = 2 * sum_k routing[t,k] *
//                 sum_r silu(dot(x[t,:], w_a[e_k,r,:])) * w_b[e_k,d,r]
// B=2,S=2048 -> 4096 tokens; D_IN=D_OUT=2048; E=16; R=16; K=2. fp32.
//
// Round 2: latency restructure. One block (256 thr) per token.
//  - Stage A: 16 groups x 16 lanes; group g owns ranks {2g,2g+1}&15 of
//    expert g>>3. All 32 dots concurrent (was: 8 serial per wave).
//    float4 accumulators -> 8 independent FMA chains/thread; 64 independent
//    global float4 loads/thread; ONE 4-step shuffle reduce (was 8x6 serial).
//  - Stage B: 32 activations cached in registers (8 float4 LDS reads),
//    thread d-strided output, contiguous 64B wb rows per thread.

#define NDIM 2048
#define RANK 16
#define TOPK 2

__device__ __forceinline__ float silu(float v) {
    return v / (1.f + __expf(-v));
}

__global__ __launch_bounds__(256) void sparse_lora_moe_kernel(
    const float* __restrict__ x,        // [T, 2048]
    const float* __restrict__ routing,  // [T, 2]
    const int*   __restrict__ idxs,     // [T, 2]
    const float* __restrict__ wa,       // [16, 16, 2048]
    const float* __restrict__ wb,       // [16, 2048, 16]
    float* __restrict__ out)            // [T, 2048]
{
    const int t   = blockIdx.x;
    const int tid = threadIdx.x;

    __shared__ float xs[NDIM];          // 8 KB
    __shared__ float as[TOPK * RANK];   // 32 silu'd activations

    // ---- stage x row into LDS (float4, coalesced) ----
    const float4* xg  = (const float4*)(x + (size_t)t * NDIM);
    float4*       xs4 = (float4*)xs;
    #pragma unroll
    for (int i = 0; i < 2; i++) xs4[tid + 256 * i] = xg[tid + 256 * i];

    const int   e0 = idxs[t * TOPK + 0];
    const int   e1 = idxs[t * TOPK + 1];
    const float r0 = routing[t * TOPK + 0];
    const float r1 = routing[t * TOPK + 1];

    __syncthreads();

    // ---- Stage A: all 32 dots concurrent ----
    const int g = tid >> 4;      // group 0..15
    const int l = tid & 15;      // lane within group
    const int p0 = 2 * g;        // pair indices 2g, 2g+1
    const int e  = (g >= 8) ? e1 : e0;
    const int rr = p0 & 15;      // rank of p0 (p1 = rr+1)

    const float4* w0 = (const float4*)(wa + ((size_t)e * RANK + rr)     * NDIM);
    const float4* w1 = (const float4*)(wa + ((size_t)e * RANK + rr + 1) * NDIM);

    float4 a0 = {0.f, 0.f, 0.f, 0.f};
    float4 a1 = {0.f, 0.f, 0.f, 0.f};
    #pragma unroll 4
    for (int i = l; i < NDIM / 4; i += 16) {
        const float4 xv  = xs4[i];
        const float4 wv0 = w0[i];
        const float4 wv1 = w1[i];
        a0.x += wv0.x * xv.x; a0.y += wv0.y * xv.y;
        a0.z += wv0.z * xv.z; a0.w += wv0.w * xv.w;
        a1.x += wv1.x * xv.x; a1.y += wv1.y * xv.y;
        a1.z += wv1.z * xv.z; a1.w += wv1.w * xv.w;
    }
    float s0 = (a0.x + a0.y) + (a0.z + a0.w);
    float s1 = (a1.x + a1.y) + (a1.z + a1.w);
    // reduce across the 16 lanes of the group (xor stays within group)
    #pragma unroll
    for (int off = 8; off > 0; off >>= 1) {
        s0 += __shfl_xor(s0, off);
        s1 += __shfl_xor(s1, off);
    }
    if (l == 0) {
        as[p0]     = silu(s0);
        as[p0 + 1] = silu(s1);
    }
    __syncthreads();

    // ---- Stage B: activations into registers, then 8 output cols/thread ----
    float4 av[8];
    #pragma unroll
    for (int q = 0; q < 8; q++) av[q] = ((const float4*)as)[q];

    const float4* wb0 = (const float4*)(wb + (size_t)e0 * NDIM * RANK);
    const float4* wb1 = (const float4*)(wb + (size_t)e1 * NDIM * RANK);
    float* orow = out + (size_t)t * NDIM;

    #pragma unroll 2
    for (int j = 0; j < NDIM / 256; j++) {
        const int d = tid + 256 * j;
        float s0v = 0.f, s1v = 0.f;
        #pragma unroll
        for (int q = 0; q < 4; q++) {
            const float4 b0 = wb0[d * 4 + q];
            const float4 b1 = wb1[d * 4 + q];
            s0v += b0.x * av[q].x + b0.y * av[q].y
                 + b0.z * av[q].z + b0.w * av[q].w;
            s1v += b1.x * av[4 + q].x + b1.y * av[4 + q].y
                 + b1.z * av[4 + q].z + b1.w * av[4 + q].w;
        }
        orow[d] = 2.0f * (r0 * s0v + r1 * s1v);
    }
}

extern "C" void kernel_launch(void* const* d_in, const int* in_sizes, int n_in,
                              void* d_out, int out_size, void* d_ws, size_t ws_size,
                              hipStream_t stream) {
    const float* x       = (const float*)d_in[0];
    const float* routing = (const float*)d_in[1];
    const int*   idxs    = (const int*)  d_in[2];
    const float* wa      = (const float*)d_in[3];
    const float* wb      = (const float*)d_in[4];
    float*       out     = (float*)d_out;

    const int tokens = 2 * 2048;  // B * S
    sparse_lora_moe_kernel<<<tokens, 256, 0, stream>>>(x, routing, idxs, wa, wb, out);
}